// Round 5
// baseline (156.742 us; speedup 1.0000x reference)
//
#include <hip/hip_runtime.h>
#include <hip/hip_bf16.h>
#include <math.h>
#include <float.h>

typedef __attribute__((ext_vector_type(8))) short short8;
typedef __attribute__((ext_vector_type(4))) float f32x4;

namespace {

constexpr int B = 256;
constexpr int M = 65536;
constexpr int D = 1024;
constexpr float DECAY_EPS = 1e-8f;
constexpr float DECAY_RATE = 0.999f;

constexpr int BN = 64;          // keys per GEMM block
constexpr int BK = 64;          // k per step
constexpr int KSTEPS = D / BK;  // 16

constexpr int CHUNKS = 8;           // top-k chunks per row
constexpr int CHUNK = M / CHUNKS;   // 8192
constexpr int NCAND = CHUNKS * 8;   // 64 candidates per row

__device__ inline ushort f2bf(float f) {
  union { float f; unsigned u; } v; v.f = f;
  unsigned r = v.u + 0x7fffu + ((v.u >> 16) & 1u);  // RNE
  return (ushort)(r >> 16);
}

__device__ inline short bfs(float f) {
  __hip_bfloat16 h = __float2bfloat16(f);  // hardware RNE cvt (v_cvt_pk fusable)
  return *reinterpret_cast<short*>(&h);
}

__device__ inline short8 pack8(float4 u, float4 v) {
  short8 r;
  r[0] = bfs(u.x); r[1] = bfs(u.y); r[2] = bfs(u.z); r[3] = bfs(u.w);
  r[4] = bfs(v.x); r[5] = bfs(v.y); r[6] = bfs(v.z); r[7] = bfs(v.w);
  return r;
}

// ---------------------------------------------------------------------------
// Kernel 1: normalize queries, emit bf16 in MFMA A-fragment order:
// qnf[(kt*16 + m_tile)*512 + lane*8 + j] = qn[m_tile*16 + (lane&15)][kt*32 + (lane>>4)*8 + j]
// ---------------------------------------------------------------------------
__global__ void prep_q_kernel(const float* __restrict__ q, ushort* __restrict__ qnf) {
  const int r = blockIdx.x;
  const int t = threadIdx.x;  // 256 threads x float4
  float4 v = reinterpret_cast<const float4*>(q + (size_t)r * D)[t];
  float ss = v.x * v.x + v.y * v.y + v.z * v.z + v.w * v.w;
#pragma unroll
  for (int off = 32; off; off >>= 1) ss += __shfl_down(ss, off, 64);
  __shared__ float red[4];
  if ((t & 63) == 0) red[t >> 6] = ss;
  __syncthreads();
  const float inv = 1.0f / fmaxf(sqrtf(red[0] + red[1] + red[2] + red[3]), DECAY_EPS);
  ushort4 o;
  o.x = f2bf(v.x * inv); o.y = f2bf(v.y * inv);
  o.z = f2bf(v.z * inv); o.w = f2bf(v.w * inv);
  const int k0 = t * 4;
  const int kt = k0 >> 5;
  const int lane_slot = (r & 15) + 16 * ((k0 & 31) >> 3);
  const int j0 = k0 & 7;  // 0 or 4
  *reinterpret_cast<ushort4*>(qnf + (size_t)(kt * 16 + (r >> 4)) * 512 + lane_slot * 8 + j0) = o;
}

// ---------------------------------------------------------------------------
// Kernel 2: bf16-MFMA scores. BM=256 (all rows) x BN=64 keys, BK=64.
// Keys staged fp32 HBM->LDS via global_load_lds (dwordx4), double-buffered,
// pre-swizzled global source so swizzled ds_read_b128 is conflict-free.
// 2-phase schedule: STAGE(next) issued first; compute covers HBM latency
// before the barrier's vmcnt drain.
// ---------------------------------------------------------------------------
__global__ __launch_bounds__(256, 3) void score_gemm_kernel(
    const ushort* __restrict__ qnf, const float* __restrict__ keys,
    const float* __restrict__ importance, const int* __restrict__ atimes,
    const int* __restrict__ acnts, const int* __restrict__ ctime,
    float* __restrict__ scores) {
  __shared__ alignas(16) float Bs[2][BN * BK];  // 2 x 16 KB fp32
  __shared__ float cscale[BN];

  const int t = threadIdx.x;
  const int lane = t & 63;
  const int w = t >> 6;
  const int h = lane >> 4;   // 0..3
  const int q = lane & 15;   // 0..15
  const int jb = blockIdx.x * BN;

  // --- staging: call i stages row r = i*16 + w*4 + h, phys chunk q holds
  //     logical chunk q ^ m(r), m(r) = ((r&3)<<1)|((r>>2)&1) = (h<<1)|(w&1).
  const int swz_w = (q ^ (h << 1) ^ (w & 1)) * 4;  // fp32 elem within 64-row
  const float* kbase = keys + (size_t)(jb + w * 4 + h) * D + swz_w;

  auto stage = [&](int s, int buf) {
#pragma unroll
    for (int i = 0; i < 4; ++i) {
      const float* gp = kbase + (size_t)i * 16 * D + s * BK;
      float* lp = &Bs[buf][i * 1024 + w * 256];  // wave-uniform; HW adds lane*16B
      __builtin_amdgcn_global_load_lds(
          (const __attribute__((address_space(1))) void*)gp,
          (__attribute__((address_space(3))) void*)lp, 16, 0, 0);
    }
  };

  // --- B-frag reads: row = nf*16+q, m(row) = ((q&3)<<1)|((q>>2)&1).
  const int mrd = ((q & 3) << 1) | ((q >> 2) & 1);

  f32x4 acc[4][4];
#pragma unroll
  for (int f = 0; f < 4; ++f)
#pragma unroll
    for (int n = 0; n < 4; ++n) acc[f][n] = (f32x4)(0.0f);

  float nrm = 0.0f;  // wave w accumulates norms of rows w*16 + q

  stage(0, 0);
  __syncthreads();

  const short8* apbase = reinterpret_cast<const short8*>(qnf);

  for (int s = 0; s < KSTEPS; ++s) {
    const int cur = s & 1;
    if (s + 1 < KSTEPS) stage(s + 1, cur ^ 1);  // async prefetch FIRST

    // A fragments for this step from L2-resident qnf (coalesced 16B/lane)
    short8 a[2][4];
    {
      const short8* ap = apbase + (size_t)(2 * s * 16 + w * 4) * 64 + lane;
#pragma unroll
      for (int ks = 0; ks < 2; ++ks)
#pragma unroll
        for (int f = 0; f < 4; ++f) a[ks][f] = ap[(ks * 16 + f) * 64];
    }

#pragma unroll
    for (int ks = 0; ks < 2; ++ks) {
      const int cbase = ks * 8 + h * 2;
      short8 bfrag[4];
#pragma unroll
      for (int nf = 0; nf < 4; ++nf) {
        const int ro = (nf * 16 + q) * 64;
        const float4 lo = *reinterpret_cast<const float4*>(
            &Bs[cur][ro + ((cbase ^ mrd) << 2)]);
        const float4 hi = *reinterpret_cast<const float4*>(
            &Bs[cur][ro + (((cbase + 1) ^ mrd) << 2)]);
        if (nf == w) {
          nrm += lo.x * lo.x + lo.y * lo.y + lo.z * lo.z + lo.w * lo.w
               + hi.x * hi.x + hi.y * hi.y + hi.z * hi.z + hi.w * hi.w;
        }
        bfrag[nf] = pack8(lo, hi);
      }
#pragma unroll
      for (int f = 0; f < 4; ++f)
#pragma unroll
        for (int nf = 0; nf < 4; ++nf)
          acc[f][nf] = __builtin_amdgcn_mfma_f32_16x16x32_bf16(
              a[ks][f], bfrag[nf], acc[f][nf], 0, 0, 0);
    }
    __syncthreads();  // drains vmcnt (stage had full compute phase to land)
  }

  // norms: lane holds partial for row w*16+q over k-elems h*8..; reduce over h
  nrm += __shfl_xor(nrm, 16, 64);
  nrm += __shfl_xor(nrm, 32, 64);
  if (lane < 16) {
    const int j = jb + w * 16 + lane;
    const float dt = (float)(ctime[0] - atimes[j]);
    const float mult = powf(DECAY_RATE, dt) * importance[j] * log1pf((float)acnts[j]);
    cscale[w * 16 + lane] = mult / fmaxf(sqrtf(nrm), DECAY_EPS);
  }
  __syncthreads();

  // epilogue: C/D layout col=lane&15, row=(lane>>4)*4+reg
#pragma unroll
  for (int f = 0; f < 4; ++f) {
    const int row0 = (w * 4 + f) * 16 + (h << 2);
#pragma unroll
    for (int nf = 0; nf < 4; ++nf) {
      const int col = nf * 16 + q;
      const float cs = cscale[col];
#pragma unroll
      for (int rr = 0; rr < 4; ++rr)
        scores[(size_t)(row0 + rr) * M + jb + col] = acc[f][nf][rr] * cs;
    }
  }
}

// ---------------------------------------------------------------------------
// Kernel 3 (stage A): per (row, chunk) top-8 indices. Branch-free insertion,
// all static indexing (registers, NOT scratch).
// ---------------------------------------------------------------------------
__global__ __launch_bounds__(256) void topk_partial_kernel(
    const float* __restrict__ scores, int* __restrict__ cand_i) {
  const int b = blockIdx.y;
  const int c = blockIdx.x;
  const int t = threadIdx.x;
  const int lane = t & 63, w = t >> 6;
  const float4* base4 = reinterpret_cast<const float4*>(scores + (size_t)b * M + (size_t)c * CHUNK);

  float s8[8];
  int i8[8];
#pragma unroll
  for (int i = 0; i < 8; ++i) { s8[i] = -FLT_MAX; i8[i] = 0; }

  auto ins = [&](float x, int j) {
    if (x > s8[0]) {
#pragma unroll
      for (int i = 0; i < 8; ++i) {
        const bool up = (i < 7) && (x > s8[i + 1]);
        const float ks = (x > s8[i]) ? x : s8[i];
        const int ki = (x > s8[i]) ? j : i8[i];
        s8[i] = up ? s8[i + 1] : ks;
        i8[i] = up ? i8[i + 1] : ki;
      }
    }
  };

  const int jbase = c * CHUNK;
  for (int it = 0; it < CHUNK / (256 * 4); ++it) {  // 8 iters
    const int slot = it * 256 + t;
    const float4 v = base4[slot];
    const int j0 = jbase + slot * 4;
    ins(v.x, j0 + 0);
    ins(v.y, j0 + 1);
    ins(v.z, j0 + 2);
    ins(v.w, j0 + 3);
  }

  __shared__ float ls[2048];
  __shared__ int li[2048];
#pragma unroll
  for (int i = 0; i < 8; ++i) { ls[t * 8 + i] = s8[i]; li[t * 8 + i] = i8[i]; }
  __syncthreads();

  __shared__ float rs4[4];
  __shared__ int rp4[4];
  for (int r = 0; r < 8; ++r) {
    float ms = -FLT_MAX;
    int mp = 0;
#pragma unroll
    for (int i = 0; i < 8; ++i) {
      const float v = ls[i * 256 + t];
      if (v > ms) { ms = v; mp = i * 256 + t; }
    }
#pragma unroll
    for (int off = 32; off; off >>= 1) {
      const float ov = __shfl_xor(ms, off, 64);
      const int op = __shfl_xor(mp, off, 64);
      if (ov > ms) { ms = ov; mp = op; }
    }
    if (lane == 0) { rs4[w] = ms; rp4[w] = mp; }
    __syncthreads();
    if (t == 0) {
      float bs = -FLT_MAX;
      int bp = 0;
#pragma unroll
      for (int i = 0; i < 4; ++i)
        if (rs4[i] > bs) { bs = rs4[i]; bp = rp4[i]; }
      cand_i[((size_t)b * CHUNKS + c) * 8 + r] = li[bp];
      ls[bp] = -FLT_MAX;
    }
    __syncthreads();
  }
}

// ---------------------------------------------------------------------------
// Kernel 4 (stage B): exact fp32 rescore of 64 candidates, top-8, softmax,
// weighted value gather. One block (512 thr = 8 waves) per row.
// ---------------------------------------------------------------------------
__global__ __launch_bounds__(512) void rescore_kernel(
    const int* __restrict__ cand_i, const float* __restrict__ query,
    const float* __restrict__ keys, const float* __restrict__ values,
    const float* __restrict__ importance, const int* __restrict__ atimes,
    const int* __restrict__ acnts, const int* __restrict__ ctime,
    float* __restrict__ outc, float* __restrict__ conf) {
  const int b = blockIdx.x;
  const int t = threadIdx.x;
  const int lane = t & 63, w = t >> 6;

  const float4* qv4 = reinterpret_cast<const float4*>(query + (size_t)b * D + lane * 16);
  float4 q0 = qv4[0], q1 = qv4[1], q2 = qv4[2], q3 = qv4[3];
  float ssq = q0.x * q0.x + q0.y * q0.y + q0.z * q0.z + q0.w * q0.w
            + q1.x * q1.x + q1.y * q1.y + q1.z * q1.z + q1.w * q1.w
            + q2.x * q2.x + q2.y * q2.y + q2.z * q2.z + q2.w * q2.w
            + q3.x * q3.x + q3.y * q3.y + q3.z * q3.z + q3.w * q3.w;
#pragma unroll
  for (int off = 32; off; off >>= 1) ssq += __shfl_xor(ssq, off, 64);
  const float qdn = fmaxf(sqrtf(ssq), DECAY_EPS);
  const int ct = ctime[0];

  __shared__ float sc[NCAND];
  __shared__ int sidx[NCAND];

  for (int u = 0; u < 8; ++u) {
    const int c = w * 8 + u;
    const int j = cand_i[(size_t)b * NCAND + c];
    const float4* kv4 = reinterpret_cast<const float4*>(keys + (size_t)j * D + lane * 16);
    const float4 k0 = kv4[0], k1 = kv4[1], k2 = kv4[2], k3 = kv4[3];
    float dd = q0.x * k0.x + q0.y * k0.y + q0.z * k0.z + q0.w * k0.w
             + q1.x * k1.x + q1.y * k1.y + q1.z * k1.z + q1.w * k1.w
             + q2.x * k2.x + q2.y * k2.y + q2.z * k2.z + q2.w * k2.w
             + q3.x * k3.x + q3.y * k3.y + q3.z * k3.z + q3.w * k3.w;
    float nn = k0.x * k0.x + k0.y * k0.y + k0.z * k0.z + k0.w * k0.w
             + k1.x * k1.x + k1.y * k1.y + k1.z * k1.z + k1.w * k1.w
             + k2.x * k2.x + k2.y * k2.y + k2.z * k2.z + k2.w * k2.w
             + k3.x * k3.x + k3.y * k3.y + k3.z * k3.z + k3.w * k3.w;
#pragma unroll
    for (int off = 32; off; off >>= 1) {
      dd += __shfl_xor(dd, off, 64);
      nn += __shfl_xor(nn, off, 64);
    }
    if (lane == 0) {
      const float dtv = (float)(ct - atimes[j]);
      const float mult = powf(DECAY_RATE, dtv) * importance[j] * log1pf((float)acnts[j]);
      sc[c] = dd / (qdn * fmaxf(sqrtf(nn), DECAY_EPS)) * mult;
      sidx[c] = j;
    }
  }
  __syncthreads();

  __shared__ float w8s[8];
  __shared__ int g8[8];
  __shared__ float confv;
  __shared__ float tls[8];
  __shared__ int tli[8];
  if (w == 0) {
    float myv = sc[lane];
    for (int r = 0; r < 8; ++r) {
      float m = myv;
      int mi = lane;
#pragma unroll
      for (int off = 32; off; off >>= 1) {
        const float ov = __shfl_xor(m, off, 64);
        const int oi = __shfl_xor(mi, off, 64);
        if (ov > m || (ov == m && oi < mi)) { m = ov; mi = oi; }
      }
      if (lane == 0) { tls[r] = m; tli[r] = mi; }
      if (lane == mi) myv = -FLT_MAX;
    }
    if (lane == 0) {
      const float mx = tls[0];
      float e[8];
      float z = 0.0f;
#pragma unroll
      for (int r = 0; r < 8; ++r) { e[r] = expf(tls[r] - mx); z += e[r]; }
      const float invz = 1.0f / z;
#pragma unroll
      for (int r = 0; r < 8; ++r) { w8s[r] = e[r] * invz; g8[r] = sidx[tli[r]]; }
      confv = w8s[0];
    }
  }
  __syncthreads();

  float2 acc = make_float2(0.0f, 0.0f);
#pragma unroll
  for (int k = 0; k < 8; ++k) {
    const float wk = w8s[k];
    const float2 v = *reinterpret_cast<const float2*>(values + (size_t)g8[k] * D + 2 * t);
    acc.x = fmaf(wk, v.x, acc.x);
    acc.y = fmaf(wk, v.y, acc.y);
  }
  *reinterpret_cast<float2*>(outc + (size_t)b * D + 2 * t) = acc;
  if (t == 0) conf[b] = confv;
}

}  // namespace

extern "C" void kernel_launch(void* const* d_in, const int* in_sizes, int n_in,
                              void* d_out, int out_size, void* d_ws, size_t ws_size,
                              hipStream_t stream) {
  const float* query = (const float*)d_in[0];
  const float* keys = (const float*)d_in[1];
  const float* values = (const float*)d_in[2];
  const float* importance = (const float*)d_in[3];
  const int* atimes = (const int*)d_in[4];
  const int* acnts = (const int*)d_in[5];
  const int* ctime = (const int*)d_in[6];

  float* out = (float*)d_out;  // combined [B*D] then confidence [B]
  ushort* qnf = (ushort*)d_ws;                                             // 512 KB
  float* scores = (float*)((char*)d_ws + (size_t)B * D * sizeof(ushort));  // 64 MB
  int* cand = (int*)(scores + (size_t)B * M);                              // 64 KB

  prep_q_kernel<<<B, 256, 0, stream>>>(query, qnf);
  score_gemm_kernel<<<M / BN, 256, 0, stream>>>(qnf, keys, importance, atimes,
                                                acnts, ctime, scores);
  dim3 gA(CHUNKS, B);
  topk_partial_kernel<<<gA, 256, 0, stream>>>(scores, cand);
  rescore_kernel<<<B, 512, 0, stream>>>(cand, query, keys, values, importance,
                                        atimes, acnts, ctime, out, out + (size_t)B * D);
}